// Round 1
// baseline (328.682 us; speedup 1.0000x reference)
//
#include <hip/hip_runtime.h>

// VecInt: scaling-and-squaring integration of a velocity field.
// vel: [2,128,128,128,3] fp32.  v = vel/2^7; 7x: v = v + warp(v, v).
// Generic step kernel: out[p] = s*v[p] + s*trilinear(v, clamp(p + s*v[p])).
// Step 1 uses s=1/128 reading vel directly (fuses the initial scale).

#define DIMSZ 128
#define NVOX_PER_B (DIMSZ * DIMSZ * DIMSZ)

__global__ __launch_bounds__(256) void vecint_step(
    const float* __restrict__ vin, float* __restrict__ vout,
    float scale, int nvox_total)
{
    int idx = blockIdx.x * blockDim.x + threadIdx.x;
    if (idx >= nvox_total) return;

    int z = idx & 127;
    int y = (idx >> 7) & 127;
    int x = (idx >> 14) & 127;
    int b = idx >> 21;

    int base = idx * 3;
    float fx = vin[base + 0] * scale;
    float fy = vin[base + 1] * scale;
    float fz = vin[base + 2] * scale;

    float lx = fminf(fmaxf((float)x + fx, 0.0f), 127.0f);
    float ly = fminf(fmaxf((float)y + fy, 0.0f), 127.0f);
    float lz = fminf(fmaxf((float)z + fz, 0.0f), 127.0f);

    float flx = floorf(lx), fly = floorf(ly), flz = floorf(lz);
    float wx1 = lx - flx, wy1 = ly - fly, wz1 = lz - flz;
    float wx0 = 1.0f - wx1, wy0 = 1.0f - wy1, wz0 = 1.0f - wz1;

    int x0 = (int)flx, y0 = (int)fly, z0 = (int)flz;
    int x1 = min(x0 + 1, 127);
    int y1 = min(y0 + 1, 127);
    int z1 = min(z0 + 1, 127);

    const float* vb = vin + (size_t)b * (NVOX_PER_B * 3);

    float ox = 0.0f, oy = 0.0f, oz = 0.0f;

#define CORNER(XX, YY, ZZ, WX, WY, WZ)                                   \
    {                                                                    \
        const float* p = vb + (((XX) << 14) + ((YY) << 7) + (ZZ)) * 3;   \
        float w = (WX) * (WY) * (WZ);                                    \
        ox += w * p[0];                                                  \
        oy += w * p[1];                                                  \
        oz += w * p[2];                                                  \
    }

    CORNER(x0, y0, z0, wx0, wy0, wz0)
    CORNER(x0, y0, z1, wx0, wy0, wz1)
    CORNER(x0, y1, z0, wx0, wy1, wz0)
    CORNER(x0, y1, z1, wx0, wy1, wz1)
    CORNER(x1, y0, z0, wx1, wy0, wz0)
    CORNER(x1, y0, z1, wx1, wy0, wz1)
    CORNER(x1, y1, z0, wx1, wy1, wz0)
    CORNER(x1, y1, z1, wx1, wy1, wz1)
#undef CORNER

    vout[base + 0] = fx + scale * ox;
    vout[base + 1] = fy + scale * oy;
    vout[base + 2] = fz + scale * oz;
}

extern "C" void kernel_launch(void* const* d_in, const int* in_sizes, int n_in,
                              void* d_out, int out_size, void* d_ws, size_t ws_size,
                              hipStream_t stream) {
    const float* vel = (const float*)d_in[0];
    float* out = (float*)d_out;
    float* ws  = (float*)d_ws;

    int nvox = in_sizes[0] / 3;               // 4,194,304 voxels (2 batches)
    int blocks = (nvox + 255) / 256;
    float s0 = 1.0f / 128.0f;                 // 1 / 2^INT_STEPS

    // 7 steps; odd steps write d_out, even write d_ws, so step 7 ends in d_out.
    vecint_step<<<blocks, 256, 0, stream>>>(vel, out, s0,  nvox);  // step 1
    vecint_step<<<blocks, 256, 0, stream>>>(out, ws,  1.f, nvox);  // step 2
    vecint_step<<<blocks, 256, 0, stream>>>(ws,  out, 1.f, nvox);  // step 3
    vecint_step<<<blocks, 256, 0, stream>>>(out, ws,  1.f, nvox);  // step 4
    vecint_step<<<blocks, 256, 0, stream>>>(ws,  out, 1.f, nvox);  // step 5
    vecint_step<<<blocks, 256, 0, stream>>>(out, ws,  1.f, nvox);  // step 6
    vecint_step<<<blocks, 256, 0, stream>>>(ws,  out, 1.f, nvox);  // step 7
}